// Round 7
// baseline (220.133 us; speedup 1.0000x reference)
//
#include <hip/hip_runtime.h>
#include <hip/hip_bf16.h>
#include <math.h>

#define BB 4
#define CC 256
#define DKK 32
#define NN 4096
// 1/sqrt(32) — folded into q at QKV epilogue; attention uses native __expf.
#define QSCALE 0.17677669529663687f

typedef __attribute__((ext_vector_type(8))) __bf16 bf16x8;
typedef __attribute__((ext_vector_type(4))) __bf16 bf16x4;
typedef __attribute__((ext_vector_type(4))) float f32x4;

// ---------------------------------------------------------------------------
// Kernel 0: fused (a) x transpose (B,C,N) fp32 -> xT (B,N,C) bf16,
//           (b) W fp32 -> bf16 Wb[320][256] (done by 80 of the blocks).
// ---------------------------------------------------------------------------
__global__ __launch_bounds__(256) void prep_kernel(
    const float* __restrict__ x, __bf16* __restrict__ xT,
    const float* __restrict__ Wq, const float* __restrict__ Wk,
    const float* __restrict__ Wv, __bf16* __restrict__ Wb)
{
    __shared__ float xs[64][68];
    const int tid = threadIdx.x;
    const int n0 = blockIdx.x * 64;
    const int c0 = blockIdx.y * 64;
    const int b  = blockIdx.z;

    if (b == 0) {
        int unit = blockIdx.y * 64 + blockIdx.x;
        if (unit < 80) {
            int i = (unit * 256 + tid) * 4;
            int row = i >> 8, col = i & 255;
            const float* src;
            if (row < 32)      src = &Wq[row * 256 + col];
            else if (row < 64) src = &Wk[(row - 32) * 256 + col];
            else               src = &Wv[(row - 64) * 256 + col];
            float4 v = *(const float4*)src;
            Wb[i]     = (__bf16)v.x;
            Wb[i + 1] = (__bf16)v.y;
            Wb[i + 2] = (__bf16)v.z;
            Wb[i + 3] = (__bf16)v.w;
        }
    }

#pragma unroll
    for (int p = 0; p < 4; p++) {
        int cc = p * 16 + (tid >> 4);
        int nf = (tid & 15) * 4;
        float4 v = *(const float4*)&x[((size_t)(b * CC + c0 + cc)) * NN + n0 + nf];
        xs[cc][nf] = v.x; xs[cc][nf + 1] = v.y; xs[cc][nf + 2] = v.z; xs[cc][nf + 3] = v.w;
    }
    __syncthreads();
    int n = tid >> 2, cs = (tid & 3) * 16;
    bf16x8 lo, hi;
#pragma unroll
    for (int j = 0; j < 8; j++) {
        lo[j] = (__bf16)xs[cs + j][n];
        hi[j] = (__bf16)xs[cs + 8 + j][n];
    }
    size_t base = ((size_t)(b * NN + n0 + n)) * CC + c0 + cs;
    *(bf16x8*)&xT[base]     = lo;
    *(bf16x8*)&xT[base + 8] = hi;
}

// ---------------------------------------------------------------------------
// Kernel 1: QKV projection — MFMA GEMM, register-bounded depth-1 prefetch.
// Block: 32 n x 320 o; wave w -> o 80w..80w+79. Grid 128 x B.
// Outputs: q,k (B,N,32) bf16 (q pre-scaled); V TILED: [chunk n/32][c/16][16][32].
// ---------------------------------------------------------------------------
__global__ __launch_bounds__(256) void qkv_kernel(
    const __bf16* __restrict__ xT, const __bf16* __restrict__ Wb,
    const float* __restrict__ bq, const float* __restrict__ bk,
    const float* __restrict__ bv,
    __bf16* __restrict__ qws, __bf16* __restrict__ kws, __bf16* __restrict__ vws)
{
    __shared__ float scr[64][33];

    const int tid = threadIdx.x;
    const int w   = tid >> 6;
    const int l   = tid & 63;
    const int l15 = l & 15;
    const int lq  = l >> 4;
    const int n0  = blockIdx.x * 32;
    const int b   = blockIdx.y;

    const __bf16* xbase = xT + ((size_t)b * NN + n0 + l15) * CC + lq * 8;
    const __bf16* wbase = Wb + (size_t)(80 * w + l15) * CC + lq * 8;

    const f32x4 zf = {0.f, 0.f, 0.f, 0.f};
    f32x4 acc[5][2];
#pragma unroll
    for (int i = 0; i < 5; i++)
#pragma unroll
        for (int j = 0; j < 2; j++) acc[i][j] = zf;

    bf16x8 bcur[2], acur[5], bnxt[2], anxt[5];
#pragma unroll
    for (int nt = 0; nt < 2; nt++) bcur[nt] = *(const bf16x8*)(xbase + nt * 16 * CC);
#pragma unroll
    for (int ot = 0; ot < 5; ot++) acur[ot] = *(const bf16x8*)(wbase + ot * 16 * CC);

#pragma unroll
    for (int ks = 0; ks < 8; ks++) {
        if (ks < 7) {
#pragma unroll
            for (int nt = 0; nt < 2; nt++)
                bnxt[nt] = *(const bf16x8*)(xbase + nt * 16 * CC + (ks + 1) * 32);
#pragma unroll
            for (int ot = 0; ot < 5; ot++)
                anxt[ot] = *(const bf16x8*)(wbase + ot * 16 * CC + (ks + 1) * 32);
        }
#pragma unroll
        for (int ot = 0; ot < 5; ot++)
#pragma unroll
            for (int nt = 0; nt < 2; nt++)
                acc[ot][nt] = __builtin_amdgcn_mfma_f32_16x16x32_bf16(acur[ot], bcur[nt], acc[ot][nt], 0, 0, 0);
        if (ks < 7) {
#pragma unroll
            for (int nt = 0; nt < 2; nt++) bcur[nt] = bnxt[nt];
#pragma unroll
            for (int ot = 0; ot < 5; ot++) acur[ot] = anxt[ot];
        }
    }

    // epilogue: D row o = 80w + ot*16 + lq*4 + r, col n = nt*16 + l15
    __bf16* vchunk = vws + (size_t)b * CC * NN + (size_t)(n0 >> 5) * 16 * 512;
#pragma unroll
    for (int ot = 0; ot < 5; ot++) {
        int ob = 80 * w + ot * 16;
#pragma unroll
        for (int nt = 0; nt < 2; nt++) {
#pragma unroll
            for (int r = 0; r < 4; r++) {
                int o = ob + lq * 4 + r;
                int n = nt * 16 + l15;
                float val = acc[ot][nt][r];
                if (ob >= 64) {
                    int c = o - 64;
                    vchunk[(5 * w - 4 + ot) * 512 + (lq * 4 + r) * 32 + n] =
                        (__bf16)(val + bv[c]);
                } else if (ob < 32) {
                    scr[o][n] = (val + bq[o]) * QSCALE;
                } else {
                    scr[o][n] = val + bk[o - 32];
                }
            }
        }
    }
    __syncthreads();
    {
        int n  = tid >> 3;            // 0..31
        int d0 = (tid & 7) * 4;       // 0..28
        bf16x4 qv, kv;
#pragma unroll
        for (int j = 0; j < 4; j++) {
            qv[j] = (__bf16)scr[d0 + j][n];
            kv[j] = (__bf16)scr[32 + d0 + j][n];
        }
        size_t base = ((size_t)b * NN + n0 + n) * DKK + d0;
        *(bf16x4*)&qws[base] = qv;
        *(bf16x4*)&kws[base] = kv;
    }
}

// ---------------------------------------------------------------------------
// Kernel 2: flash attention — N-SPLIT waves, zero-redundancy, zero-barrier
// main loop. Block: 64 m (grid 256, 1/CU), 4 waves. Wave w owns n-chunk
// (ic*4+w)*32 each iteration (32 iterations x 128 n): computes its own P
// (8 KQ MFMA + 32 exp, NO redundancy), round-trips P through WAVE-PRIVATE
// LDS (PST=40 -> <=2-way banks), then PV over ALL 256 c for its n-chunk
// (64 MFMA, acc = 64 f32x4 = full O partial). No cross-wave data in the
// main loop at all. Epilogue: cross-wave O + l reduction through LDS.
// ---------------------------------------------------------------------------
#define PST 40                     // P row stride (bf16): 80B rows, 2-way free
#define MST 68                     // O-reduce row stride (dwords), 16B-aligned

__global__ __launch_bounds__(256, 1) void attn_kernel(
    const __bf16* __restrict__ qb, const __bf16* __restrict__ kb,
    const __bf16* __restrict__ vt, const float* __restrict__ x,
    float* __restrict__ out)
{
    // layout: [0,40960)   pbuf: 4 waves x 2 bufs x 64 rows x PST bf16
    //         [0,69632)   Ored (epilogue overlay): 4 regions x 64 x MST fp32
    //         [69632,70656) Ls[4][64], [70656,70912) Linv[64]
    __shared__ __align__(16) unsigned char smem[70912];
    __bf16* pw   = (__bf16*)smem + (threadIdx.x >> 6) * 2 * (64 * PST);
    float*  Ored = (float*)smem;
    float*  Ls   = (float*)(smem + 69632);
    float*  Linv = (float*)(smem + 70656);

    const int tid = threadIdx.x;
    const int w   = tid >> 6;
    const int l   = tid & 63;
    const int l15 = l & 15;
    const int lq  = l >> 4;

    // XCD swizzle: batch pinned to an XCD pair -> K/V/Q stay L2-resident
    const int beta = blockIdx.x;
    const int b    = (beta >> 1) & 3;
    const int mt   = ((beta >> 3) << 1) | (beta & 1);   // 0..63
    const int m0   = mt * 64;

    const __bf16* qbb = qb + (size_t)b * NN * DKK;
    const __bf16* kbb = kb + (size_t)b * NN * DKK;
    const __bf16* vtb = vt + (size_t)b * CC * NN;

    // q B-frags for the 4 m-tiles
    bf16x8 qa[4];
#pragma unroll
    for (int af = 0; af < 4; af++)
        qa[af] = *(const bf16x8*)(qbb + (size_t)(m0 + af * 16 + l15) * DKK + lq * 8);

    const __bf16* kstrip = kbb + (size_t)(w * 32 + l15) * DKK + lq * 8;   // + ic*128*DKK
    const __bf16* vstrip = vtb + (size_t)w * 8192 + l15 * 32 + lq * 8;    // + ic*32768 + ct*512

    const f32x4 zf = {0.f, 0.f, 0.f, 0.f};
    f32x4 acc[4][16];
#pragma unroll
    for (int i = 0; i < 4; i++)
#pragma unroll
        for (int j = 0; j < 16; j++) acc[i][j] = zf;
    float lacc[4] = {0.f, 0.f, 0.f, 0.f};

    // ---- prologue: P(0) -> buf 0; prefetch k(1) ----
    bf16x8 kA0 = *(const bf16x8*)kstrip;
    bf16x8 kA1 = *(const bf16x8*)(kstrip + 16 * DKK);
#pragma unroll
    for (int af = 0; af < 4; af++) {
        f32x4 e0 = __builtin_amdgcn_mfma_f32_16x16x32_bf16(kA0, qa[af], zf, 0, 0, 0);
        f32x4 e1 = __builtin_amdgcn_mfma_f32_16x16x32_bf16(kA1, qa[af], zf, 0, 0, 0);
        bf16x4 p0, p1;
#pragma unroll
        for (int r = 0; r < 4; r++) {
            float v0 = __expf(e0[r]); lacc[af] += v0; p0[r] = (__bf16)v0;
            float v1 = __expf(e1[r]); lacc[af] += v1; p1[r] = (__bf16)v1;
        }
        *(bf16x4*)&pw[(af * 16 + l15) * PST + lq * 4]      = p0;
        *(bf16x4*)&pw[(af * 16 + l15) * PST + 16 + lq * 4] = p1;
    }
    kA0 = *(const bf16x8*)(kstrip + (size_t)128 * DKK);
    kA1 = *(const bf16x8*)(kstrip + (size_t)144 * DKK);

    // ---- main loop: iteration ic = V(ic) loads, pf<-P(ic), KQ+exp->P(ic+1),
    //      PV(ic). Purely intra-wave; no barriers. ----
#pragma unroll 1
    for (int ic = 0; ic < 31; ic++) {
        const int cur = ic & 1;

        bf16x8 vf[16];
#pragma unroll
        for (int ct = 0; ct < 16; ct++)
            vf[ct] = *(const bf16x8*)(vstrip + (size_t)ic * 32768 + ct * 512);

        bf16x8 pf[4];
#pragma unroll
        for (int af = 0; af < 4; af++)
            pf[af] = *(const bf16x8*)&pw[cur * (64 * PST) + (af * 16 + l15) * PST + lq * 8];

        // KQ(ic+1) + exp into the other wave-private buffer
#pragma unroll
        for (int af = 0; af < 4; af++) {
            f32x4 e0 = __builtin_amdgcn_mfma_f32_16x16x32_bf16(kA0, qa[af], zf, 0, 0, 0);
            f32x4 e1 = __builtin_amdgcn_mfma_f32_16x16x32_bf16(kA1, qa[af], zf, 0, 0, 0);
            bf16x4 p0, p1;
#pragma unroll
            for (int r = 0; r < 4; r++) {
                float v0 = __expf(e0[r]); lacc[af] += v0; p0[r] = (__bf16)v0;
                float v1 = __expf(e1[r]); lacc[af] += v1; p1[r] = (__bf16)v1;
            }
            *(bf16x4*)&pw[(cur ^ 1) * (64 * PST) + (af * 16 + l15) * PST + lq * 4]      = p0;
            *(bf16x4*)&pw[(cur ^ 1) * (64 * PST) + (af * 16 + l15) * PST + 16 + lq * 4] = p1;
        }
        // prefetch k(ic+2) (OOB at tail lands in adjacent ws region — unused)
        kA0 = *(const bf16x8*)(kstrip + (size_t)(ic + 2) * 128 * DKK);
        kA1 = *(const bf16x8*)(kstrip + (size_t)((ic + 2) * 128 + 16) * DKK);

        // PV(ic): O[c][m] += V[c][n] * P[m][n] over all 16 c-tiles
#pragma unroll
        for (int ct = 0; ct < 16; ct++)
#pragma unroll
            for (int af = 0; af < 4; af++)
                acc[af][ct] = __builtin_amdgcn_mfma_f32_16x16x32_bf16(vf[ct], pf[af], acc[af][ct], 0, 0, 0);
    }

    // ---- peel: PV(31) ----
    {
        bf16x8 vf[16];
#pragma unroll
        for (int ct = 0; ct < 16; ct++)
            vf[ct] = *(const bf16x8*)(vstrip + (size_t)31 * 32768 + ct * 512);
        bf16x8 pf[4];
#pragma unroll
        for (int af = 0; af < 4; af++)
            pf[af] = *(const bf16x8*)&pw[(31 & 1) * (64 * PST) + (af * 16 + l15) * PST + lq * 8];
#pragma unroll
        for (int ct = 0; ct < 16; ct++)
#pragma unroll
            for (int af = 0; af < 4; af++)
                acc[af][ct] = __builtin_amdgcn_mfma_f32_16x16x32_bf16(vf[ct], pf[af], acc[af][ct], 0, 0, 0);
    }

    // ---- l: intra-wave reduce, publish per-wave partials ----
#pragma unroll
    for (int af = 0; af < 4; af++) {
        lacc[af] += __shfl_xor(lacc[af], 16, 64);
        lacc[af] += __shfl_xor(lacc[af], 32, 64);
    }
    if (lq == 0) {
#pragma unroll
        for (int af = 0; af < 4; af++) Ls[w * 64 + af * 16 + l15] = lacc[af];
    }
    __syncthreads();
    if (tid < 64)
        Linv[tid] = 1.0f / (Ls[tid] + Ls[64 + tid] + Ls[128 + tid] + Ls[192 + tid]);

    // ---- epilogue: cross-wave O reduce in 4 c-quarters via LDS ----
#pragma unroll
    for (int q = 0; q < 4; q++) {
        if (q > 0) __syncthreads();       // prior quarter's reads done
        // write this wave's partial for c-quarter q
#pragma unroll
        for (int cg = 0; cg < 4; cg++) {
#pragma unroll
            for (int af = 0; af < 4; af++) {
#pragma unroll
                for (int r = 0; r < 4; r++)
                    Ored[w * (64 * MST) + (cg * 16 + lq * 4 + r) * MST + af * 16 + l15] =
                        acc[af][q * 4 + cg][r];
            }
        }
        __syncthreads();
        // sum 4 partials, normalize, residual, store
        const int cl = tid >> 2;          // 0..63
        const int mo = (tid & 3) * 16;    // 0,16,32,48
#pragma unroll
        for (int j = 0; j < 4; j++) {
            int mi = mo + 4 * j;
            f32x4 s = *(const f32x4*)&Ored[cl * MST + mi];
            s = s + *(const f32x4*)&Ored[1 * (64 * MST) + cl * MST + mi];
            s = s + *(const f32x4*)&Ored[2 * (64 * MST) + cl * MST + mi];
            s = s + *(const f32x4*)&Ored[3 * (64 * MST) + cl * MST + mi];
            f32x4 li = *(const f32x4*)&Linv[mi];
            size_t gi = ((size_t)(b * CC + q * 64 + cl)) * NN + m0 + mi;
            f32x4 xr = *(const f32x4*)&x[gi];
            *(f32x4*)&out[gi] = s * li + xr;
        }
    }
}

extern "C" void kernel_launch(void* const* d_in, const int* in_sizes, int n_in,
                              void* d_out, int out_size, void* d_ws, size_t ws_size,
                              hipStream_t stream) {
    const float* x  = (const float*)d_in[0];
    const float* Wq = (const float*)d_in[1];
    const float* bq = (const float*)d_in[2];
    const float* Wk = (const float*)d_in[3];
    const float* bk = (const float*)d_in[4];
    const float* Wv = (const float*)d_in[5];
    const float* bv = (const float*)d_in[6];
    float* out = (float*)d_out;

    __bf16* qws = (__bf16*)d_ws;                       // B*N*32
    __bf16* kws = qws + (size_t)BB * NN * DKK;         // B*N*32
    __bf16* vws = kws + (size_t)BB * NN * DKK;         // B*C*N (tiled)
    __bf16* Wb  = vws + (size_t)BB * CC * NN;          // 320*256
    __bf16* xT  = Wb  + (size_t)320 * CC;              // B*N*C

    prep_kernel<<<dim3(64, 4, BB), 256, 0, stream>>>(x, xT, Wq, Wk, Wv, Wb);
    qkv_kernel <<<dim3(128, BB), 256, 0, stream>>>(xT, Wb, bq, bk, bv, qws, kws, vws);
    attn_kernel<<<dim3(256), 256, 0, stream>>>(qws, kws, vws, x, out);
}

// Round 8
// 152.348 us; speedup vs baseline: 1.4449x; 1.4449x over previous
//
#include <hip/hip_runtime.h>
#include <hip/hip_bf16.h>
#include <math.h>

#define BB 4
#define CC 256
#define DKK 32
#define NN 4096
// 1/sqrt(32) — folded into q at QKV epilogue; attention uses native __expf.
#define QSCALE 0.17677669529663687f

typedef __attribute__((ext_vector_type(8))) __bf16 bf16x8;
typedef __attribute__((ext_vector_type(4))) __bf16 bf16x4;
typedef __attribute__((ext_vector_type(4))) float f32x4;

// ---------------------------------------------------------------------------
// Kernel 0: fused (a) x transpose (B,C,N) fp32 -> xT (B,N,C) bf16,
//           (b) W fp32 -> bf16 Wb[320][256] (done by 80 of the blocks).
// ---------------------------------------------------------------------------
__global__ __launch_bounds__(256) void prep_kernel(
    const float* __restrict__ x, __bf16* __restrict__ xT,
    const float* __restrict__ Wq, const float* __restrict__ Wk,
    const float* __restrict__ Wv, __bf16* __restrict__ Wb)
{
    __shared__ float xs[64][68];
    const int tid = threadIdx.x;
    const int n0 = blockIdx.x * 64;
    const int c0 = blockIdx.y * 64;
    const int b  = blockIdx.z;

    if (b == 0) {
        int unit = blockIdx.y * 64 + blockIdx.x;
        if (unit < 80) {
            int i = (unit * 256 + tid) * 4;
            int row = i >> 8, col = i & 255;
            const float* src;
            if (row < 32)      src = &Wq[row * 256 + col];
            else if (row < 64) src = &Wk[(row - 32) * 256 + col];
            else               src = &Wv[(row - 64) * 256 + col];
            float4 v = *(const float4*)src;
            Wb[i]     = (__bf16)v.x;
            Wb[i + 1] = (__bf16)v.y;
            Wb[i + 2] = (__bf16)v.z;
            Wb[i + 3] = (__bf16)v.w;
        }
    }

#pragma unroll
    for (int p = 0; p < 4; p++) {
        int cc = p * 16 + (tid >> 4);
        int nf = (tid & 15) * 4;
        float4 v = *(const float4*)&x[((size_t)(b * CC + c0 + cc)) * NN + n0 + nf];
        xs[cc][nf] = v.x; xs[cc][nf + 1] = v.y; xs[cc][nf + 2] = v.z; xs[cc][nf + 3] = v.w;
    }
    __syncthreads();
    int n = tid >> 2, cs = (tid & 3) * 16;
    bf16x8 lo, hi;
#pragma unroll
    for (int j = 0; j < 8; j++) {
        lo[j] = (__bf16)xs[cs + j][n];
        hi[j] = (__bf16)xs[cs + 8 + j][n];
    }
    size_t base = ((size_t)(b * NN + n0 + n)) * CC + c0 + cs;
    *(bf16x8*)&xT[base]     = lo;
    *(bf16x8*)&xT[base + 8] = hi;
}

// ---------------------------------------------------------------------------
// Kernel 1: QKV projection — MFMA GEMM, register-bounded depth-1 prefetch.
// Block: 32 n x 320 o; wave w -> o 80w..80w+79. Grid 128 x B.
// Outputs: q,k (B,N,32) bf16 (q pre-scaled); V TILED: [chunk n/32][c/16][16][32].
// ---------------------------------------------------------------------------
__global__ __launch_bounds__(256) void qkv_kernel(
    const __bf16* __restrict__ xT, const __bf16* __restrict__ Wb,
    const float* __restrict__ bq, const float* __restrict__ bk,
    const float* __restrict__ bv,
    __bf16* __restrict__ qws, __bf16* __restrict__ kws, __bf16* __restrict__ vws)
{
    __shared__ float scr[64][33];

    const int tid = threadIdx.x;
    const int w   = tid >> 6;
    const int l   = tid & 63;
    const int l15 = l & 15;
    const int lq  = l >> 4;
    const int n0  = blockIdx.x * 32;
    const int b   = blockIdx.y;

    const __bf16* xbase = xT + ((size_t)b * NN + n0 + l15) * CC + lq * 8;
    const __bf16* wbase = Wb + (size_t)(80 * w + l15) * CC + lq * 8;

    const f32x4 zf = {0.f, 0.f, 0.f, 0.f};
    f32x4 acc[5][2];
#pragma unroll
    for (int i = 0; i < 5; i++)
#pragma unroll
        for (int j = 0; j < 2; j++) acc[i][j] = zf;

    bf16x8 bcur[2], acur[5], bnxt[2], anxt[5];
#pragma unroll
    for (int nt = 0; nt < 2; nt++) bcur[nt] = *(const bf16x8*)(xbase + nt * 16 * CC);
#pragma unroll
    for (int ot = 0; ot < 5; ot++) acur[ot] = *(const bf16x8*)(wbase + ot * 16 * CC);

#pragma unroll
    for (int ks = 0; ks < 8; ks++) {
        if (ks < 7) {
#pragma unroll
            for (int nt = 0; nt < 2; nt++)
                bnxt[nt] = *(const bf16x8*)(xbase + nt * 16 * CC + (ks + 1) * 32);
#pragma unroll
            for (int ot = 0; ot < 5; ot++)
                anxt[ot] = *(const bf16x8*)(wbase + ot * 16 * CC + (ks + 1) * 32);
        }
#pragma unroll
        for (int ot = 0; ot < 5; ot++)
#pragma unroll
            for (int nt = 0; nt < 2; nt++)
                acc[ot][nt] = __builtin_amdgcn_mfma_f32_16x16x32_bf16(acur[ot], bcur[nt], acc[ot][nt], 0, 0, 0);
        if (ks < 7) {
#pragma unroll
            for (int nt = 0; nt < 2; nt++) bcur[nt] = bnxt[nt];
#pragma unroll
            for (int ot = 0; ot < 5; ot++) acur[ot] = anxt[ot];
        }
    }

    // epilogue: D row o = 80w + ot*16 + lq*4 + r, col n = nt*16 + l15
    __bf16* vchunk = vws + (size_t)b * CC * NN + (size_t)(n0 >> 5) * 16 * 512;
#pragma unroll
    for (int ot = 0; ot < 5; ot++) {
        int ob = 80 * w + ot * 16;
#pragma unroll
        for (int nt = 0; nt < 2; nt++) {
#pragma unroll
            for (int r = 0; r < 4; r++) {
                int o = ob + lq * 4 + r;
                int n = nt * 16 + l15;
                float val = acc[ot][nt][r];
                if (ob >= 64) {
                    int c = o - 64;
                    vchunk[(5 * w - 4 + ot) * 512 + (lq * 4 + r) * 32 + n] =
                        (__bf16)(val + bv[c]);
                } else if (ob < 32) {
                    scr[o][n] = (val + bq[o]) * QSCALE;
                } else {
                    scr[o][n] = val + bk[o - 32];
                }
            }
        }
    }
    __syncthreads();
    {
        int n  = tid >> 3;            // 0..31
        int d0 = (tid & 7) * 4;       // 0..28
        bf16x4 qv, kv;
#pragma unroll
        for (int j = 0; j < 4; j++) {
            qv[j] = (__bf16)scr[d0 + j][n];
            kv[j] = (__bf16)scr[32 + d0 + j][n];
        }
        size_t base = ((size_t)b * NN + n0 + n) * DKK + d0;
        *(bf16x4*)&qws[base] = qv;
        *(bf16x4*)&kws[base] = kv;
    }
}

// ---------------------------------------------------------------------------
// Kernel 2: flash attention — n-split waves, zero-barrier main loop,
// 64m x 128c blocks, grid 512 (2 blocks/CU -> 2 waves/SIMD for latency
// hiding). Wave w owns n-chunk (ic*4+w)*32: computes its own P (8 KQ MFMA +
// 32 exp), round-trips through WAVE-PRIVATE LDS (PST=40, <=2-way banks),
// then PV over this block's 128-c half (32 MFMA). acc[4][8]=128 regs
// (AGPR-able), V frags loaded in groups of 4 (live <=8 regs) -> ~250 regs
// per wave, fits 2 waves/SIMD without spill. Epilogue: cross-wave O + l
// reduce via LDS in 32-c quarters.
// ---------------------------------------------------------------------------
#define PST 40                     // P row stride (bf16): 80B rows, 2-way free
#define MST 68                     // O-reduce row stride (dwords)
#define PWSZ (64 * PST)            // one P buffer (elems)

__global__ __launch_bounds__(256, 2) void attn_kernel(
    const __bf16* __restrict__ qb, const __bf16* __restrict__ kb,
    const __bf16* __restrict__ vt, const float* __restrict__ x,
    float* __restrict__ out)
{
    // [0, 40960)       pbuf: 4 waves x 2 bufs x 64 x PST bf16
    // [0, 34816)       Ored overlay (epilogue): 4 waves x 32 x MST fp32
    // [40960, 41984)   Ls[4][64]
    // [41984, 42240)   Linv[64]
    __shared__ __align__(16) unsigned char smem[42240];
    __bf16* pw   = (__bf16*)smem + (threadIdx.x >> 6) * 2 * PWSZ;
    float*  Ls   = (float*)(smem + 40960);
    float*  Linv = (float*)(smem + 41984);

    const int tid = threadIdx.x;
    const int w   = tid >> 6;
    const int l   = tid & 63;
    const int l15 = l & 15;
    const int lq  = l >> 4;

    // XCD swizzle: batch pinned to an XCD pair -> K/V/Q stay L2-resident
    const int beta = blockIdx.x;
    const int b    = (beta >> 1) & 3;
    const int ch   = (beta >> 3) & 1;                        // c-half
    const int mt   = ((beta >> 4) << 1) | (beta & 1);        // 0..63
    const int m0   = mt * 64;

    const __bf16* qbb = qb + (size_t)b * NN * DKK;
    const __bf16* kbb = kb + (size_t)b * NN * DKK;
    const __bf16* vtb = vt + (size_t)b * CC * NN;

    // q B-frags for the 4 m-tiles
    bf16x8 qa[4];
#pragma unroll
    for (int af = 0; af < 4; af++)
        qa[af] = *(const bf16x8*)(qbb + (size_t)(m0 + af * 16 + l15) * DKK + lq * 8);

    // wave w's n-strips: chunk j = ic*4 + w
    const __bf16* kstrip = kbb + (size_t)(w * 32 + l15) * DKK + lq * 8;     // + ic*128*DKK
    const __bf16* vstrip = vtb + (size_t)w * 8192 + (size_t)ch * 4096
                               + l15 * 32 + lq * 8;                          // + ic*32768 + ct*512

    const f32x4 zf = {0.f, 0.f, 0.f, 0.f};
    f32x4 acc[4][8];
#pragma unroll
    for (int i = 0; i < 4; i++)
#pragma unroll
        for (int j = 0; j < 8; j++) acc[i][j] = zf;
    float lacc[4] = {0.f, 0.f, 0.f, 0.f};

    // ---- prologue: P(0) -> buf 0; prefetch k(1) ----
    bf16x8 kA0 = *(const bf16x8*)kstrip;
    bf16x8 kA1 = *(const bf16x8*)(kstrip + 16 * DKK);
#pragma unroll
    for (int af = 0; af < 4; af++) {
        f32x4 e0 = __builtin_amdgcn_mfma_f32_16x16x32_bf16(kA0, qa[af], zf, 0, 0, 0);
        f32x4 e1 = __builtin_amdgcn_mfma_f32_16x16x32_bf16(kA1, qa[af], zf, 0, 0, 0);
        bf16x4 p0, p1;
#pragma unroll
        for (int r = 0; r < 4; r++) {
            float v0 = __expf(e0[r]); lacc[af] += v0; p0[r] = (__bf16)v0;
            float v1 = __expf(e1[r]); lacc[af] += v1; p1[r] = (__bf16)v1;
        }
        *(bf16x4*)&pw[(af * 16 + l15) * PST + lq * 4]      = p0;
        *(bf16x4*)&pw[(af * 16 + l15) * PST + 16 + lq * 4] = p1;
    }
    kA0 = *(const bf16x8*)(kstrip + (size_t)128 * DKK);
    kA1 = *(const bf16x8*)(kstrip + (size_t)144 * DKK);

    // ---- main loop: zero barriers, purely intra-wave ----
#pragma unroll 2
    for (int ic = 0; ic < 31; ic++) {
        const int cur = ic & 1;
        const __bf16* vch = vstrip + (size_t)ic * 32768;

        // V group 0 in flight early (KQ/exp covers its latency)
        bf16x8 vfC[4], vfN[4];
#pragma unroll
        for (int ct = 0; ct < 4; ct++)
            vfC[ct] = *(const bf16x8*)(vch + ct * 512);

        bf16x8 pf[4];
#pragma unroll
        for (int af = 0; af < 4; af++)
            pf[af] = *(const bf16x8*)&pw[cur * PWSZ + (af * 16 + l15) * PST + lq * 8];

        // KQ(ic+1) + exp into the other wave-private buffer
#pragma unroll
        for (int af = 0; af < 4; af++) {
            f32x4 e0 = __builtin_amdgcn_mfma_f32_16x16x32_bf16(kA0, qa[af], zf, 0, 0, 0);
            f32x4 e1 = __builtin_amdgcn_mfma_f32_16x16x32_bf16(kA1, qa[af], zf, 0, 0, 0);
            bf16x4 p0, p1;
#pragma unroll
            for (int r = 0; r < 4; r++) {
                float v0 = __expf(e0[r]); lacc[af] += v0; p0[r] = (__bf16)v0;
                float v1 = __expf(e1[r]); lacc[af] += v1; p1[r] = (__bf16)v1;
            }
            *(bf16x4*)&pw[(cur ^ 1) * PWSZ + (af * 16 + l15) * PST + lq * 4]      = p0;
            *(bf16x4*)&pw[(cur ^ 1) * PWSZ + (af * 16 + l15) * PST + 16 + lq * 4] = p1;
        }
        // prefetch k(ic+2) (OOB at tail lands in adjacent ws region — unused)
        kA0 = *(const bf16x8*)(kstrip + (size_t)(ic + 2) * 128 * DKK);
        kA1 = *(const bf16x8*)(kstrip + (size_t)((ic + 2) * 128 + 16) * DKK);

        // PV(ic): 2 c-groups of 4 tiles, one-group prefetch
#pragma unroll
        for (int ct = 0; ct < 4; ct++)
            vfN[ct] = *(const bf16x8*)(vch + (4 + ct) * 512);
#pragma unroll
        for (int ct = 0; ct < 4; ct++)
#pragma unroll
            for (int af = 0; af < 4; af++)
                acc[af][ct] = __builtin_amdgcn_mfma_f32_16x16x32_bf16(vfC[ct], pf[af], acc[af][ct], 0, 0, 0);
#pragma unroll
        for (int ct = 0; ct < 4; ct++)
#pragma unroll
            for (int af = 0; af < 4; af++)
                acc[af][4 + ct] = __builtin_amdgcn_mfma_f32_16x16x32_bf16(vfN[ct], pf[af], acc[af][4 + ct], 0, 0, 0);
    }

    // ---- peel: PV(31) ----
    {
        const __bf16* vch = vstrip + (size_t)31 * 32768;
        bf16x8 pf[4];
#pragma unroll
        for (int af = 0; af < 4; af++)
            pf[af] = *(const bf16x8*)&pw[(31 & 1) * PWSZ + (af * 16 + l15) * PST + lq * 8];
        bf16x8 vfC[4], vfN[4];
#pragma unroll
        for (int ct = 0; ct < 4; ct++) vfC[ct] = *(const bf16x8*)(vch + ct * 512);
#pragma unroll
        for (int ct = 0; ct < 4; ct++) vfN[ct] = *(const bf16x8*)(vch + (4 + ct) * 512);
#pragma unroll
        for (int ct = 0; ct < 4; ct++)
#pragma unroll
            for (int af = 0; af < 4; af++)
                acc[af][ct] = __builtin_amdgcn_mfma_f32_16x16x32_bf16(vfC[ct], pf[af], acc[af][ct], 0, 0, 0);
#pragma unroll
        for (int ct = 0; ct < 4; ct++)
#pragma unroll
            for (int af = 0; af < 4; af++)
                acc[af][4 + ct] = __builtin_amdgcn_mfma_f32_16x16x32_bf16(vfN[ct], pf[af], acc[af][4 + ct], 0, 0, 0);
    }

    // ---- l: intra-wave reduce, publish per-wave partials ----
#pragma unroll
    for (int af = 0; af < 4; af++) {
        lacc[af] += __shfl_xor(lacc[af], 16, 64);
        lacc[af] += __shfl_xor(lacc[af], 32, 64);
    }
    if (lq == 0) {
#pragma unroll
        for (int af = 0; af < 4; af++) Ls[w * 64 + af * 16 + l15] = lacc[af];
    }
    __syncthreads();
    if (tid < 64)
        Linv[tid] = 1.0f / (Ls[tid] + Ls[64 + tid] + Ls[128 + tid] + Ls[192 + tid]);

    // ---- epilogue: cross-wave O reduce in 4 quarters of 32 c ----
    float* Ored = (float*)smem + w * (32 * MST);
#pragma unroll
    for (int q = 0; q < 4; q++) {
        if (q > 0) __syncthreads();       // prior quarter's reads done
#pragma unroll
        for (int ctp = 0; ctp < 2; ctp++) {
            int ct = 2 * q + ctp;
#pragma unroll
            for (int af = 0; af < 4; af++) {
#pragma unroll
                for (int r = 0; r < 4; r++)
                    Ored[(ctp * 16 + lq * 4 + r) * MST + af * 16 + l15] = acc[af][ct][r];
            }
        }
        __syncthreads();
        // sum 4 wave-partials, normalize, residual, store
        const int cl  = tid >> 3;         // 0..31 (c within quarter)
        const int mi0 = (tid & 7) * 8;    // m offset
        const float* Ob = (const float*)smem + cl * MST;
#pragma unroll
        for (int j = 0; j < 2; j++) {
            int mi = mi0 + 4 * j;
            f32x4 s = *(const f32x4*)&Ob[mi];
            s = s + *(const f32x4*)&Ob[1 * (32 * MST) + mi];
            s = s + *(const f32x4*)&Ob[2 * (32 * MST) + mi];
            s = s + *(const f32x4*)&Ob[3 * (32 * MST) + mi];
            f32x4 li = *(const f32x4*)&Linv[mi];
            int c = ch * 128 + q * 32 + cl;
            size_t gi = ((size_t)(b * CC + c)) * NN + m0 + mi;
            f32x4 xr = *(const f32x4*)&x[gi];
            *(f32x4*)&out[gi] = s * li + xr;
        }
    }
}

extern "C" void kernel_launch(void* const* d_in, const int* in_sizes, int n_in,
                              void* d_out, int out_size, void* d_ws, size_t ws_size,
                              hipStream_t stream) {
    const float* x  = (const float*)d_in[0];
    const float* Wq = (const float*)d_in[1];
    const float* bq = (const float*)d_in[2];
    const float* Wk = (const float*)d_in[3];
    const float* bk = (const float*)d_in[4];
    const float* Wv = (const float*)d_in[5];
    const float* bv = (const float*)d_in[6];
    float* out = (float*)d_out;

    __bf16* qws = (__bf16*)d_ws;                       // B*N*32
    __bf16* kws = qws + (size_t)BB * NN * DKK;         // B*N*32
    __bf16* vws = kws + (size_t)BB * NN * DKK;         // B*C*N (tiled)
    __bf16* Wb  = vws + (size_t)BB * CC * NN;          // 320*256
    __bf16* xT  = Wb  + (size_t)320 * CC;              // B*N*C

    prep_kernel<<<dim3(64, 4, BB), 256, 0, stream>>>(x, xT, Wq, Wk, Wv, Wb);
    qkv_kernel <<<dim3(128, BB), 256, 0, stream>>>(xT, Wb, bq, bk, bv, qws, kws, vws);
    attn_kernel<<<dim3(512), 256, 0, stream>>>(qws, kws, vws, x, out);
}